// Round 20
// baseline (235.503 us; speedup 1.0000x reference)
//
#include <hip/hip_runtime.h>
#include <hip/hip_fp16.h>
#include <math.h>

constexpr int Lq = 8, Cq = 16, Hq = 240, Wq = 480, MIDq = 8, SEM = 4;
constexpr int HWq = Hq * Wq;

__device__ __forceinline__ float sigmoidf_(float v) { return 1.0f / (1.0f + expf(-v)); }

struct alignas(16) h8 { __half v[8]; };

// conv1: x (L,16,H,W) -> silu -> f1 (L,8,H,W), 3x3 SAME zero-pad.
// R20: m0-style deep load batch. m0 proves 32 independent strided loads/thread
// sustain 7.4 TB/s; conv1's 9-deep load->wait->FMA pipeline got 1.0 TB/s.
// Batch ALL 48 float4 (16ch x 3rows) before any FMA; asm memory barrier pins
// the loads above the compute (R13/R14: allocator sank them, VGPR 36/68);
// launch_bounds(128,1) -> 512-VGPR budget, no spill (R12 failed via spills:
// WRITE=87MB). Edge scalars JIT per-ic (L1 hits). FMA chains R13-exact.
__global__ __launch_bounds__(128, 1) void k_conv1(const float* __restrict__ x,
                        const float* __restrict__ w1,
                        const float* __restrict__ b1, float* __restrict__ f1) {
    int b = blockIdx.x;
    int l = b & 7, y = b >> 3;
    int t = threadIdx.x;
    if (t >= 120) return;
    int xi = t * 4;
    int yy0 = y > 0 ? y - 1 : 0;
    int yy2 = y < Hq - 1 ? y + 1 : Hq - 1;
    float v0 = y > 0 ? 1.f : 0.f;
    float v2 = y < Hq - 1 ? 1.f : 0.f;
    bool lok = xi > 0, rok = xi + 4 < Wq;
    const float* xb = x + (size_t)l * Cq * HWq;

    // ---- phase 1: 48 independent float4 loads, all in flight ----
    float4 mid[Cq][3];
#pragma unroll
    for (int ic = 0; ic < Cq; ic++) {
        const float* cp = xb + (size_t)ic * HWq;
        mid[ic][0] = *(const float4*)(cp + (size_t)yy0 * Wq + xi);
        mid[ic][1] = *(const float4*)(cp + (size_t)y * Wq + xi);
        mid[ic][2] = *(const float4*)(cp + (size_t)yy2 * Wq + xi);
    }
    asm volatile("" ::: "memory");   // pin loads above compute (no sinking)

    float acc[MIDq][4];
#pragma unroll
    for (int m = 0; m < MIDq; m++) {
        float bv = b1[m];
#pragma unroll
        for (int o = 0; o < 4; o++) acc[m][o] = bv;
    }
    // ---- phase 2: per-ic FMA blocks; edges JIT (L1-hit lines) ----
#pragma unroll
    for (int ic = 0; ic < Cq; ic++) {
        const float* p0 = xb + (size_t)ic * HWq + (size_t)yy0 * Wq;
        const float* p1 = xb + (size_t)ic * HWq + (size_t)y * Wq;
        const float* p2 = xb + (size_t)ic * HWq + (size_t)yy2 * Wq;
        float l0 = lok ? p0[xi - 1] : 0.f;
        float l1 = lok ? p1[xi - 1] : 0.f;
        float l2 = lok ? p2[xi - 1] : 0.f;
        float r0 = rok ? p0[xi + 4] : 0.f;
        float r1 = rok ? p1[xi + 4] : 0.f;
        float r2 = rok ? p2[xi + 4] : 0.f;
        float4 m0v = mid[ic][0], m1v = mid[ic][1], m2v = mid[ic][2];
        float in0[6] = {l0 * v0, m0v.x * v0, m0v.y * v0, m0v.z * v0, m0v.w * v0, r0 * v0};
        float in1[6] = {l1, m1v.x, m1v.y, m1v.z, m1v.w, r1};
        float in2[6] = {l2 * v2, m2v.x * v2, m2v.y * v2, m2v.z * v2, m2v.w * v2, r2 * v2};
        const float* wic = w1 + ic * 9;
#pragma unroll
        for (int m = 0; m < MIDq; m++) {
            const float* wp = wic + (size_t)m * (Cq * 9);
            float w00 = wp[0], w01 = wp[1], w02 = wp[2];
            float w10 = wp[3], w11 = wp[4], w12 = wp[5];
            float w20 = wp[6], w21 = wp[7], w22 = wp[8];
#pragma unroll
            for (int o = 0; o < 4; o++) {
                float a = acc[m][o];
                a = fmaf(w00, in0[o], fmaf(w01, in0[o + 1], fmaf(w02, in0[o + 2], a)));
                a = fmaf(w10, in1[o], fmaf(w11, in1[o + 1], fmaf(w12, in1[o + 2], a)));
                a = fmaf(w20, in2[o], fmaf(w21, in2[o + 1], fmaf(w22, in2[o + 2], a)));
                acc[m][o] = a;
            }
        }
    }
    size_t rowoff = (size_t)y * Wq + xi;
#pragma unroll
    for (int m = 0; m < MIDq; m++) {
        float4 v;
        float a0 = acc[m][0], a1 = acc[m][1], a2 = acc[m][2], a3 = acc[m][3];
        v.x = a0 * sigmoidf_(a0);
        v.y = a1 * sigmoidf_(a1);
        v.z = a2 * sigmoidf_(a2);
        v.w = a3 * sigmoidf_(a3);
        *(float4*)(f1 + (size_t)(l * MIDq + m) * HWq + rowoff) = v;
    }
}

// conv2: f1 (L,8,H,W) -> f (L,2,H,W). Same deep-batch treatment (24 float4).
__global__ __launch_bounds__(128, 2) void k_conv2(const float* __restrict__ f1,
                        const float* __restrict__ w2,
                        const float* __restrict__ b2, float* __restrict__ f) {
    int b = blockIdx.x;
    int l = b & 7, y = b >> 3;
    int t = threadIdx.x;
    if (t >= 120) return;
    int xi = t * 4;
    int yy0 = y > 0 ? y - 1 : 0;
    int yy2 = y < Hq - 1 ? y + 1 : Hq - 1;
    float v0 = y > 0 ? 1.f : 0.f;
    float v2 = y < Hq - 1 ? 1.f : 0.f;
    bool lok = xi > 0, rok = xi + 4 < Wq;
    const float* fb = f1 + (size_t)l * MIDq * HWq;

    float4 mid[MIDq][3];
#pragma unroll
    for (int ic = 0; ic < MIDq; ic++) {
        const float* cp = fb + (size_t)ic * HWq;
        mid[ic][0] = *(const float4*)(cp + (size_t)yy0 * Wq + xi);
        mid[ic][1] = *(const float4*)(cp + (size_t)y * Wq + xi);
        mid[ic][2] = *(const float4*)(cp + (size_t)yy2 * Wq + xi);
    }
    asm volatile("" ::: "memory");

    float acc[2][4];
#pragma unroll
    for (int m = 0; m < 2; m++) {
        float bv = b2[m];
#pragma unroll
        for (int o = 0; o < 4; o++) acc[m][o] = bv;
    }
#pragma unroll
    for (int ic = 0; ic < MIDq; ic++) {
        const float* p0 = fb + (size_t)ic * HWq + (size_t)yy0 * Wq;
        const float* p1 = fb + (size_t)ic * HWq + (size_t)y * Wq;
        const float* p2 = fb + (size_t)ic * HWq + (size_t)yy2 * Wq;
        float l0 = lok ? p0[xi - 1] : 0.f;
        float l1 = lok ? p1[xi - 1] : 0.f;
        float l2 = lok ? p2[xi - 1] : 0.f;
        float r0 = rok ? p0[xi + 4] : 0.f;
        float r1 = rok ? p1[xi + 4] : 0.f;
        float r2 = rok ? p2[xi + 4] : 0.f;
        float4 m0v = mid[ic][0], m1v = mid[ic][1], m2v = mid[ic][2];
        float in0[6] = {l0 * v0, m0v.x * v0, m0v.y * v0, m0v.z * v0, m0v.w * v0, r0 * v0};
        float in1[6] = {l1, m1v.x, m1v.y, m1v.z, m1v.w, r1};
        float in2[6] = {l2 * v2, m2v.x * v2, m2v.y * v2, m2v.z * v2, m2v.w * v2, r2 * v2};
        const float* wic = w2 + ic * 9;
#pragma unroll
        for (int m = 0; m < 2; m++) {
            const float* wp = wic + (size_t)m * (MIDq * 9);
            float w00 = wp[0], w01 = wp[1], w02 = wp[2];
            float w10 = wp[3], w11 = wp[4], w12 = wp[5];
            float w20 = wp[6], w21 = wp[7], w22 = wp[8];
#pragma unroll
            for (int o = 0; o < 4; o++) {
                float a = acc[m][o];
                a = fmaf(w00, in0[o], fmaf(w01, in0[o + 1], fmaf(w02, in0[o + 2], a)));
                a = fmaf(w10, in1[o], fmaf(w11, in1[o + 1], fmaf(w12, in1[o + 2], a)));
                a = fmaf(w20, in2[o], fmaf(w21, in2[o + 1], fmaf(w22, in2[o + 2], a)));
                acc[m][o] = a;
            }
        }
    }
    size_t rowoff = (size_t)y * Wq + xi;
#pragma unroll
    for (int m = 0; m < 2; m++) {
        float4 v = {acc[m][0], acc[m][1], acc[m][2], acc[m][3]};
        *(float4*)(f + (size_t)(l * 2 + m) * HWq + rowoff) = v;
    }
}

// sobel (wrap-x, edge-y) + metric + tanh -> flow (L,2,H,W) (R5 exact)
__global__ void k_flow(const float* __restrict__ f, float* __restrict__ flow) {
    int idx = blockIdx.x * blockDim.x + threadIdx.x;
    if (idx >= Lq * HWq) return;
    int l = idx / HWq, rem = idx % HWq, y = rem / Wq, x = rem % Wq;
    const float* phi = f + (size_t)(l * 2 + 0) * HWq;
    const float* psi = f + (size_t)(l * 2 + 1) * HWq;
    float ph[3][3], ps[3][3];
#pragma unroll
    for (int i = 0; i < 3; i++) {
        int yy = y + i - 1;
        yy = yy < 0 ? 0 : (yy >= Hq ? Hq - 1 : yy);
#pragma unroll
        for (int j = 0; j < 3; j++) {
            int xx = x + j - 1;
            xx = (xx + Wq) % Wq;
            ph[i][j] = phi[yy * Wq + xx];
            ps[i][j] = psi[yy * Wq + xx];
        }
    }
    float gxp = (ph[0][2] - ph[0][0]) + 2.f * (ph[1][2] - ph[1][0]) + (ph[2][2] - ph[2][0]);
    float gyp = (ph[2][0] + 2.f * ph[2][1] + ph[2][2]) - (ph[0][0] + 2.f * ph[0][1] + ph[0][2]);
    float gxs = (ps[0][2] - ps[0][0]) + 2.f * (ps[1][2] - ps[1][0]) + (ps[2][2] - ps[2][0]);
    float gys = (ps[2][0] + 2.f * ps[2][1] + ps[2][2]) - (ps[0][0] + 2.f * ps[0][1] + ps[0][2]);
    float latf = (float)(-M_PI * 0.5 + (double)y * (M_PI / (double)(Hq - 1)));
    float metric = (float)(1.0 / (cos((double)latf) + 1e-6));
    float u = gxp * metric - gys;
    float v = gyp + gxs * metric;
    flow[(size_t)(l * 2 + 0) * HWq + rem] = tanhf(u);
    flow[(size_t)(l * 2 + 1) * HWq + rem] = tanhf(v);
}

// one-time: m0[px][c] = mean_r h0[c][px][r] -> fp16 (h0: (C,H,W,R) fp32)
__global__ void k_m0(const float* __restrict__ h0, h8* __restrict__ m0) {
    int px = blockIdx.x * 256 + threadIdx.x;
    const float4* h4 = (const float4*)h0;
#pragma unroll
    for (int half = 0; half < 2; half++) {
        h8 o;
#pragma unroll
        for (int cc = 0; cc < 8; cc++) {
            int c = half * 8 + cc;
            float4 a = h4[(size_t)(c * HWq + px) * 2];
            float4 b = h4[(size_t)(c * HWq + px) * 2 + 1];
            o.v[cc] = __float2half((a.x + a.y + a.z + a.w + b.x + b.y + b.z + b.w) * 0.125f);
        }
        m0[(size_t)px * 2 + half] = o;
    }
}

// Fused scan step (R19 exact: fp16 m, one 16B gather per corner per lane).
__global__ __launch_bounds__(1024) void k_step(const h8* __restrict__ min_,
                       h8* __restrict__ mout, const float* __restrict__ flow_l,
                       const float* __restrict__ xl, const float* __restrict__ listT,
                       int l,
                       const float* __restrict__ sw1, const float* __restrict__ sb1,
                       const float* __restrict__ sw2, const float* __restrict__ sb2,
                       float* __restrict__ out_l) {
    constexpr int STR = 17;
    __shared__ float sm[Wq * STR];
    __shared__ float csum[Cq];
    __shared__ float zl[SEM];
    __shared__ float gl[Cq];

    int y = blockIdx.x;
    int t = threadIdx.x;
    int wave = t >> 6, lane = t & 63;
    bool act = t < 2 * Wq;
    int px = act ? (t >> 1) : (Wq - 1);
    int half = t & 1;
    int c0 = half * 8;

    float dt = listT[l];
    float mn[8];
    {
        float u = flow_l[y * Wq + px];
        float v = flow_l[HWq + y * Wq + px];
        float gx = (px * (2.0f / (Wq - 1)) - 1.0f) - u * dt;
        float gy = (y * (2.0f / (Hq - 1)) - 1.0f) - v * dt;
        float xp = fminf(fmaxf((gx + 1.0f) * (Wq * 0.5f) - 0.5f, 0.0f), (float)(Wq - 1));
        float yp = fminf(fmaxf((gy + 1.0f) * (Hq * 0.5f) - 0.5f, 0.0f), (float)(Hq - 1));
        float x0f = floorf(xp), y0f = floorf(yp);
        float wx = xp - x0f, wy = yp - y0f;
        int x0 = (int)x0f, y0 = (int)y0f;
        int x1 = min(x0 + 1, Wq - 1), y1 = min(y0 + 1, Hq - 1);
        h8 A = min_[(size_t)(y0 * Wq + x0) * 2 + half];
        h8 B = min_[(size_t)(y0 * Wq + x1) * 2 + half];
        h8 C = min_[(size_t)(y1 * Wq + x0) * 2 + half];
        h8 D = min_[(size_t)(y1 * Wq + x1) * 2 + half];
        float w00 = (1.f - wx) * (1.f - wy), w01 = wx * (1.f - wy);
        float w10 = (1.f - wx) * wy, w11 = wx * wy;
        const float* xb = xl + y * Wq + px;
#pragma unroll
        for (int j = 0; j < 8; j++) {
            float xv = xb[(size_t)(c0 + j) * HWq];
            mn[j] = w00 * __half2float(A.v[j]) + w01 * __half2float(B.v[j]) +
                    w10 * __half2float(C.v[j]) + w11 * __half2float(D.v[j]) + xv;
        }
    }
    if (act) {
        h8 o;
#pragma unroll
        for (int j = 0; j < 8; j++) o.v[j] = __float2half(mn[j]);
        mout[(size_t)(y * Wq + px) * 2 + half] = o;
#pragma unroll
        for (int j = 0; j < 8; j++) sm[px * STR + c0 + j] = mn[j];
    }
    __syncthreads();
    {
        float s = 0.f;
#pragma unroll
        for (int k = 0; k < 8; k++) {
            int p = k * 64 + lane;
            if (p < Wq) s += sm[p * STR + wave];
        }
#pragma unroll
        for (int off = 32; off > 0; off >>= 1) s += __shfl_down(s, off, 64);
        if (lane == 0) csum[wave] = s;
    }
    __syncthreads();
    if (t < SEM) {
        float a = sb1[t];
#pragma unroll
        for (int i = 0; i < Cq; i++) a = fmaf(sw1[t * Cq + i], csum[i] * (1.0f / Wq), a);
        zl[t] = a * sigmoidf_(a);
    }
    __syncthreads();
    if (t < Cq) {
        float a = sb2[t];
#pragma unroll
        for (int m = 0; m < SEM; m++) a = fmaf(sw2[t * SEM + m], zl[m], a);
        gl[t] = sigmoidf_(a);
    }
    __syncthreads();
    if (act) {
        float* ob = out_l + y * Wq + px;
#pragma unroll
        for (int j = 0; j < 8; j++)
            ob[(size_t)(c0 + j) * HWq] = mn[j] * gl[c0 + j];
    }
}

extern "C" void kernel_launch(void* const* d_in, const int* in_sizes, int n_in,
                              void* d_out, int out_size, void* d_ws, size_t ws_size,
                              hipStream_t stream) {
    const float* x = (const float*)d_in[0];
    const float* h0 = (const float*)d_in[1];
    const float* listT = (const float*)d_in[2];
    const float* hw1 = (const float*)d_in[3];
    const float* hb1 = (const float*)d_in[4];
    const float* hw2 = (const float*)d_in[5];
    const float* hb2 = (const float*)d_in[6];
    const float* sw1 = (const float*)d_in[7];
    const float* sb1 = (const float*)d_in[8];
    const float* sw2 = (const float*)d_in[9];
    const float* sb2 = (const float*)d_in[10];
    float* out = (float*)d_out;
    char* ws = (char*)d_ws;

    size_t off = 0;
    float* flow = (float*)(ws + off); off += sizeof(float) * (size_t)Lq * 2 * HWq;
    float* f    = (float*)(ws + off); off += sizeof(float) * (size_t)Lq * 2 * HWq;
    float* f1   = (float*)(ws + off); off += sizeof(float) * (size_t)Lq * MIDq * HWq;
    h8* mA      = (h8*)(ws + off);    off += sizeof(h8) * (size_t)HWq * 2;
    h8* mB      = (h8*)(ws + off);    off += sizeof(h8) * (size_t)HWq * 2;

    k_conv1<<<Lq * Hq, 128, 0, stream>>>(x, hw1, hb1, f1);
    k_conv2<<<Lq * Hq, 128, 0, stream>>>(f1, hw2, hb2, f);
    k_flow<<<(Lq * HWq + 255) / 256, 256, 0, stream>>>(f, flow);
    k_m0<<<HWq / 256, 256, 0, stream>>>(h0, mA);

    h8* bufs[2] = {mA, mB};
    for (int l = 0; l < Lq; l++) {
        h8* min_ = bufs[l & 1];
        h8* mout = bufs[(l + 1) & 1];
        k_step<<<Hq, 1024, 0, stream>>>(min_, mout, flow + (size_t)l * 2 * HWq,
                                        x + (size_t)l * Cq * HWq, listT, l,
                                        sw1, sb1, sw2, sb2,
                                        out + (size_t)l * Cq * HWq);
    }
}

// Round 21
// 161.026 us; speedup vs baseline: 1.4625x; 1.4625x over previous
//
#include <hip/hip_runtime.h>
#include <hip/hip_fp16.h>
#include <math.h>

constexpr int Lq = 8, Cq = 16, Hq = 240, Wq = 480, MIDq = 8, SEM = 4;
constexpr int HWq = Hq * Wq;

__device__ __forceinline__ float sigmoidf_(float v) { return 1.0f / (1.0f + expf(-v)); }

struct alignas(16) h8 { __half v[8]; };

// conv1: R13-exact (measured floor 57.6us across 11 restructures R6-R20).
__global__ __launch_bounds__(128, 4) void k_conv1(const float* __restrict__ x,
                        const float* __restrict__ w1,
                        const float* __restrict__ b1, float* __restrict__ f1) {
    int b = blockIdx.x;
    int l = b & 7, y = b >> 3;
    int t = threadIdx.x;
    if (t >= 120) return;
    int xi = t * 4;
    float acc[MIDq][4];
#pragma unroll
    for (int m = 0; m < MIDq; m++) {
        float bv = b1[m];
#pragma unroll
        for (int o = 0; o < 4; o++) acc[m][o] = bv;
    }
    int yy0 = y > 0 ? y - 1 : 0;
    int yy2 = y < Hq - 1 ? y + 1 : Hq - 1;
    float v0 = y > 0 ? 1.f : 0.f;
    float v2 = y < Hq - 1 ? 1.f : 0.f;
    bool lok = xi > 0, rok = xi + 4 < Wq;
    const float* xb = x + (size_t)l * Cq * HWq;
#pragma unroll 1
    for (int ic = 0; ic < Cq; ic++) {
        const float* p0 = xb + (size_t)ic * HWq + yy0 * Wq;
        const float* p1 = xb + (size_t)ic * HWq + y * Wq;
        const float* p2 = xb + (size_t)ic * HWq + yy2 * Wq;
        float4 m0 = *(const float4*)(p0 + xi);
        float4 m1 = *(const float4*)(p1 + xi);
        float4 m2 = *(const float4*)(p2 + xi);
        float l0 = lok ? p0[xi - 1] : 0.f;
        float l1 = lok ? p1[xi - 1] : 0.f;
        float l2 = lok ? p2[xi - 1] : 0.f;
        float r0 = rok ? p0[xi + 4] : 0.f;
        float r1 = rok ? p1[xi + 4] : 0.f;
        float r2 = rok ? p2[xi + 4] : 0.f;
        float in0[6] = {l0 * v0, m0.x * v0, m0.y * v0, m0.z * v0, m0.w * v0, r0 * v0};
        float in1[6] = {l1, m1.x, m1.y, m1.z, m1.w, r1};
        float in2[6] = {l2 * v2, m2.x * v2, m2.y * v2, m2.z * v2, m2.w * v2, r2 * v2};
        const float* wic = w1 + ic * 9;
#pragma unroll
        for (int m = 0; m < MIDq; m++) {
            const float* wp = wic + (size_t)m * (Cq * 9);
            float w00 = wp[0], w01 = wp[1], w02 = wp[2];
            float w10 = wp[3], w11 = wp[4], w12 = wp[5];
            float w20 = wp[6], w21 = wp[7], w22 = wp[8];
#pragma unroll
            for (int o = 0; o < 4; o++) {
                float a = acc[m][o];
                a = fmaf(w00, in0[o], fmaf(w01, in0[o + 1], fmaf(w02, in0[o + 2], a)));
                a = fmaf(w10, in1[o], fmaf(w11, in1[o + 1], fmaf(w12, in1[o + 2], a)));
                a = fmaf(w20, in2[o], fmaf(w21, in2[o + 1], fmaf(w22, in2[o + 2], a)));
                acc[m][o] = a;
            }
        }
    }
    size_t rowoff = (size_t)y * Wq + xi;
#pragma unroll
    for (int m = 0; m < MIDq; m++) {
        float4 v;
        float a0 = acc[m][0], a1 = acc[m][1], a2 = acc[m][2], a3 = acc[m][3];
        v.x = a0 * sigmoidf_(a0);
        v.y = a1 * sigmoidf_(a1);
        v.z = a2 * sigmoidf_(a2);
        v.w = a3 * sigmoidf_(a3);
        *(float4*)(f1 + (size_t)(l * MIDq + m) * HWq + rowoff) = v;
    }
}

// conv2: R13-exact.
__global__ __launch_bounds__(128, 4) void k_conv2(const float* __restrict__ f1,
                        const float* __restrict__ w2,
                        const float* __restrict__ b2, float* __restrict__ f) {
    int b = blockIdx.x;
    int l = b & 7, y = b >> 3;
    int t = threadIdx.x;
    if (t >= 120) return;
    int xi = t * 4;
    float acc[2][4];
#pragma unroll
    for (int m = 0; m < 2; m++) {
        float bv = b2[m];
#pragma unroll
        for (int o = 0; o < 4; o++) acc[m][o] = bv;
    }
    int yy0 = y > 0 ? y - 1 : 0;
    int yy2 = y < Hq - 1 ? y + 1 : Hq - 1;
    float v0 = y > 0 ? 1.f : 0.f;
    float v2 = y < Hq - 1 ? 1.f : 0.f;
    bool lok = xi > 0, rok = xi + 4 < Wq;
    const float* fb = f1 + (size_t)l * MIDq * HWq;
#pragma unroll 1
    for (int ic = 0; ic < MIDq; ic++) {
        const float* p0 = fb + (size_t)ic * HWq + yy0 * Wq;
        const float* p1 = fb + (size_t)ic * HWq + y * Wq;
        const float* p2 = fb + (size_t)ic * HWq + yy2 * Wq;
        float4 m0 = *(const float4*)(p0 + xi);
        float4 m1 = *(const float4*)(p1 + xi);
        float4 m2 = *(const float4*)(p2 + xi);
        float l0 = lok ? p0[xi - 1] : 0.f;
        float l1 = lok ? p1[xi - 1] : 0.f;
        float l2 = lok ? p2[xi - 1] : 0.f;
        float r0 = rok ? p0[xi + 4] : 0.f;
        float r1 = rok ? p1[xi + 4] : 0.f;
        float r2 = rok ? p2[xi + 4] : 0.f;
        float in0[6] = {l0 * v0, m0.x * v0, m0.y * v0, m0.z * v0, m0.w * v0, r0 * v0};
        float in1[6] = {l1, m1.x, m1.y, m1.z, m1.w, r1};
        float in2[6] = {l2 * v2, m2.x * v2, m2.y * v2, m2.z * v2, m2.w * v2, r2 * v2};
        const float* wic = w2 + ic * 9;
#pragma unroll
        for (int m = 0; m < 2; m++) {
            const float* wp = wic + (size_t)m * (MIDq * 9);
            float w00 = wp[0], w01 = wp[1], w02 = wp[2];
            float w10 = wp[3], w11 = wp[4], w12 = wp[5];
            float w20 = wp[6], w21 = wp[7], w22 = wp[8];
#pragma unroll
            for (int o = 0; o < 4; o++) {
                float a = acc[m][o];
                a = fmaf(w00, in0[o], fmaf(w01, in0[o + 1], fmaf(w02, in0[o + 2], a)));
                a = fmaf(w10, in1[o], fmaf(w11, in1[o + 1], fmaf(w12, in1[o + 2], a)));
                a = fmaf(w20, in2[o], fmaf(w21, in2[o + 1], fmaf(w22, in2[o + 2], a)));
                acc[m][o] = a;
            }
        }
    }
    size_t rowoff = (size_t)y * Wq + xi;
#pragma unroll
    for (int m = 0; m < 2; m++) {
        float4 v = {acc[m][0], acc[m][1], acc[m][2], acc[m][3]};
        *(float4*)(f + (size_t)(l * 2 + m) * HWq + rowoff) = v;
    }
}

// one-time: m0[px][c] = mean_r h0[c][px][r] -> fp16 (h0: (C,H,W,R) fp32)
__global__ void k_m0(const float* __restrict__ h0, h8* __restrict__ m0) {
    int px = blockIdx.x * 256 + threadIdx.x;
    const float4* h4 = (const float4*)h0;
#pragma unroll
    for (int half = 0; half < 2; half++) {
        h8 o;
#pragma unroll
        for (int cc = 0; cc < 8; cc++) {
            int c = half * 8 + cc;
            float4 a = h4[(size_t)(c * HWq + px) * 2];
            float4 b = h4[(size_t)(c * HWq + px) * 2 + 1];
            o.v[cc] = __float2half((a.x + a.y + a.z + a.w + b.x + b.y + b.z + b.w) * 0.125f);
        }
        m0[(size_t)px * 2 + half] = o;
    }
}

// Fused scan step. R21: k_flow fused in — stage 3 f-rows (2ch) in LDS,
// compute sobel+metric+tanh in-register (identical arithmetic to k_flow),
// then the R19 gather/rowsum/SE/out. flow buffer + dispatch eliminated.
__global__ __launch_bounds__(1024) void k_step(const h8* __restrict__ min_,
                       h8* __restrict__ mout, const float* __restrict__ f_l,
                       const float* __restrict__ xl, const float* __restrict__ listT,
                       int l,
                       const float* __restrict__ sw1, const float* __restrict__ sb1,
                       const float* __restrict__ sw2, const float* __restrict__ sb2,
                       float* __restrict__ out_l) {
    constexpr int STR = 17;
    __shared__ float sm[Wq * STR];          // reused: f-stage (2880) then transpose
    __shared__ float csum[Cq];
    __shared__ float zl[SEM];
    __shared__ float gl[Cq];

    int y = blockIdx.x;
    int t = threadIdx.x;
    int wave = t >> 6, lane = t & 63;
    bool act = t < 2 * Wq;
    int px = act ? (t >> 1) : (Wq - 1);
    int half = t & 1;
    int c0 = half * 8;

    // ---- phase 0: stage f rows y-1..y+1 (edge-clamped), 2 channels ----
    int ry0 = y > 0 ? y - 1 : 0;
    int ry1 = y;
    int ry2 = y < Hq - 1 ? y + 1 : Hq - 1;
    int ry[3] = {ry0, ry1, ry2};
    for (int s = t; s < 2 * 3 * Wq; s += 1024) {
        int ch = s / (3 * Wq);
        int rem = s - ch * 3 * Wq;
        int i = rem / Wq;
        int xx = rem - i * Wq;
        sm[s] = f_l[(size_t)ch * HWq + (size_t)ry[i] * Wq + xx];
    }
    __syncthreads();

    // ---- phase 1: sobel + metric + tanh (identical math to k_flow) ----
    float u, v;
    {
        int xm = px == 0 ? Wq - 1 : px - 1;
        int xp2 = px == Wq - 1 ? 0 : px + 1;
        int cols[3] = {xm, px, xp2};
        float ph[3][3], ps[3][3];
#pragma unroll
        for (int i = 0; i < 3; i++) {
#pragma unroll
            for (int j = 0; j < 3; j++) {
                ph[i][j] = sm[i * Wq + cols[j]];
                ps[i][j] = sm[(3 + i) * Wq + cols[j]];
            }
        }
        float gxp = (ph[0][2] - ph[0][0]) + 2.f * (ph[1][2] - ph[1][0]) + (ph[2][2] - ph[2][0]);
        float gyp = (ph[2][0] + 2.f * ph[2][1] + ph[2][2]) - (ph[0][0] + 2.f * ph[0][1] + ph[0][2]);
        float gxs = (ps[0][2] - ps[0][0]) + 2.f * (ps[1][2] - ps[1][0]) + (ps[2][2] - ps[2][0]);
        float gys = (ps[2][0] + 2.f * ps[2][1] + ps[2][2]) - (ps[0][0] + 2.f * ps[0][1] + ps[0][2]);
        float latf = (float)(-M_PI * 0.5 + (double)y * (M_PI / (double)(Hq - 1)));
        float metric = (float)(1.0 / (cos((double)latf) + 1e-6));
        u = tanhf(gxp * metric - gys);
        v = tanhf(gyp + gxs * metric);
    }
    __syncthreads();   // sm about to be overwritten by transpose

    // ---- phase 2: gather + x add (R19 exact) ----
    float dt = listT[l];
    float mn[8];
    {
        float gx = (px * (2.0f / (Wq - 1)) - 1.0f) - u * dt;
        float gy = (y * (2.0f / (Hq - 1)) - 1.0f) - v * dt;
        float xp = fminf(fmaxf((gx + 1.0f) * (Wq * 0.5f) - 0.5f, 0.0f), (float)(Wq - 1));
        float yp = fminf(fmaxf((gy + 1.0f) * (Hq * 0.5f) - 0.5f, 0.0f), (float)(Hq - 1));
        float x0f = floorf(xp), y0f = floorf(yp);
        float wx = xp - x0f, wy = yp - y0f;
        int x0 = (int)x0f, y0 = (int)y0f;
        int x1 = min(x0 + 1, Wq - 1), y1 = min(y0 + 1, Hq - 1);
        h8 A = min_[(size_t)(y0 * Wq + x0) * 2 + half];
        h8 B = min_[(size_t)(y0 * Wq + x1) * 2 + half];
        h8 C = min_[(size_t)(y1 * Wq + x0) * 2 + half];
        h8 D = min_[(size_t)(y1 * Wq + x1) * 2 + half];
        float w00 = (1.f - wx) * (1.f - wy), w01 = wx * (1.f - wy);
        float w10 = (1.f - wx) * wy, w11 = wx * wy;
        const float* xb = xl + y * Wq + px;
#pragma unroll
        for (int j = 0; j < 8; j++) {
            float xv = xb[(size_t)(c0 + j) * HWq];
            mn[j] = w00 * __half2float(A.v[j]) + w01 * __half2float(B.v[j]) +
                    w10 * __half2float(C.v[j]) + w11 * __half2float(D.v[j]) + xv;
        }
    }
    if (act) {
        h8 o;
#pragma unroll
        for (int j = 0; j < 8; j++) o.v[j] = __float2half(mn[j]);
        mout[(size_t)(y * Wq + px) * 2 + half] = o;
#pragma unroll
        for (int j = 0; j < 8; j++) sm[px * STR + c0 + j] = mn[j];
    }
    __syncthreads();
    {
        float s = 0.f;
#pragma unroll
        for (int k = 0; k < 8; k++) {
            int p = k * 64 + lane;
            if (p < Wq) s += sm[p * STR + wave];
        }
#pragma unroll
        for (int off = 32; off > 0; off >>= 1) s += __shfl_down(s, off, 64);
        if (lane == 0) csum[wave] = s;
    }
    __syncthreads();
    if (t < SEM) {
        float a = sb1[t];
#pragma unroll
        for (int i = 0; i < Cq; i++) a = fmaf(sw1[t * Cq + i], csum[i] * (1.0f / Wq), a);
        zl[t] = a * sigmoidf_(a);
    }
    __syncthreads();
    if (t < Cq) {
        float a = sb2[t];
#pragma unroll
        for (int m = 0; m < SEM; m++) a = fmaf(sw2[t * SEM + m], zl[m], a);
        gl[t] = sigmoidf_(a);
    }
    __syncthreads();
    if (act) {
        float* ob = out_l + y * Wq + px;
#pragma unroll
        for (int j = 0; j < 8; j++)
            ob[(size_t)(c0 + j) * HWq] = mn[j] * gl[c0 + j];
    }
}

extern "C" void kernel_launch(void* const* d_in, const int* in_sizes, int n_in,
                              void* d_out, int out_size, void* d_ws, size_t ws_size,
                              hipStream_t stream) {
    const float* x = (const float*)d_in[0];
    const float* h0 = (const float*)d_in[1];
    const float* listT = (const float*)d_in[2];
    const float* hw1 = (const float*)d_in[3];
    const float* hb1 = (const float*)d_in[4];
    const float* hw2 = (const float*)d_in[5];
    const float* hb2 = (const float*)d_in[6];
    const float* sw1 = (const float*)d_in[7];
    const float* sb1 = (const float*)d_in[8];
    const float* sw2 = (const float*)d_in[9];
    const float* sb2 = (const float*)d_in[10];
    float* out = (float*)d_out;
    char* ws = (char*)d_ws;

    size_t off = 0;
    float* f    = (float*)(ws + off); off += sizeof(float) * (size_t)Lq * 2 * HWq;
    float* f1   = (float*)(ws + off); off += sizeof(float) * (size_t)Lq * MIDq * HWq;
    h8* mA      = (h8*)(ws + off);    off += sizeof(h8) * (size_t)HWq * 2;
    h8* mB      = (h8*)(ws + off);    off += sizeof(h8) * (size_t)HWq * 2;

    k_conv1<<<Lq * Hq, 128, 0, stream>>>(x, hw1, hb1, f1);
    k_conv2<<<Lq * Hq, 128, 0, stream>>>(f1, hw2, hb2, f);
    k_m0<<<HWq / 256, 256, 0, stream>>>(h0, mA);

    h8* bufs[2] = {mA, mB};
    for (int l = 0; l < Lq; l++) {
        h8* min_ = bufs[l & 1];
        h8* mout = bufs[(l + 1) & 1];
        k_step<<<Hq, 1024, 0, stream>>>(min_, mout, f + (size_t)l * 2 * HWq,
                                        x + (size_t)l * Cq * HWq, listT, l,
                                        sw1, sb1, sw2, sb2,
                                        out + (size_t)l * Cq * HWq);
    }
}

// Round 22
// 153.085 us; speedup vs baseline: 1.5384x; 1.0519x over previous
//
#include <hip/hip_runtime.h>
#include <hip/hip_fp16.h>
#include <math.h>

constexpr int Lq = 8, Cq = 16, Hq = 240, Wq = 480, MIDq = 8, SEM = 4;
constexpr int HWq = Hq * Wq;

__device__ __forceinline__ float sigmoidf_(float v) { return 1.0f / (1.0f + expf(-v)); }

struct alignas(16) h8 { __half v[8]; };

// conv1: R13-exact (measured floor 57.6us across 12 restructures R6-R21).
__global__ __launch_bounds__(128, 4) void k_conv1(const float* __restrict__ x,
                        const float* __restrict__ w1,
                        const float* __restrict__ b1, float* __restrict__ f1) {
    int b = blockIdx.x;
    int l = b & 7, y = b >> 3;
    int t = threadIdx.x;
    if (t >= 120) return;
    int xi = t * 4;
    float acc[MIDq][4];
#pragma unroll
    for (int m = 0; m < MIDq; m++) {
        float bv = b1[m];
#pragma unroll
        for (int o = 0; o < 4; o++) acc[m][o] = bv;
    }
    int yy0 = y > 0 ? y - 1 : 0;
    int yy2 = y < Hq - 1 ? y + 1 : Hq - 1;
    float v0 = y > 0 ? 1.f : 0.f;
    float v2 = y < Hq - 1 ? 1.f : 0.f;
    bool lok = xi > 0, rok = xi + 4 < Wq;
    const float* xb = x + (size_t)l * Cq * HWq;
#pragma unroll 1
    for (int ic = 0; ic < Cq; ic++) {
        const float* p0 = xb + (size_t)ic * HWq + yy0 * Wq;
        const float* p1 = xb + (size_t)ic * HWq + y * Wq;
        const float* p2 = xb + (size_t)ic * HWq + yy2 * Wq;
        float4 m0 = *(const float4*)(p0 + xi);
        float4 m1 = *(const float4*)(p1 + xi);
        float4 m2 = *(const float4*)(p2 + xi);
        float l0 = lok ? p0[xi - 1] : 0.f;
        float l1 = lok ? p1[xi - 1] : 0.f;
        float l2 = lok ? p2[xi - 1] : 0.f;
        float r0 = rok ? p0[xi + 4] : 0.f;
        float r1 = rok ? p1[xi + 4] : 0.f;
        float r2 = rok ? p2[xi + 4] : 0.f;
        float in0[6] = {l0 * v0, m0.x * v0, m0.y * v0, m0.z * v0, m0.w * v0, r0 * v0};
        float in1[6] = {l1, m1.x, m1.y, m1.z, m1.w, r1};
        float in2[6] = {l2 * v2, m2.x * v2, m2.y * v2, m2.z * v2, m2.w * v2, r2 * v2};
        const float* wic = w1 + ic * 9;
#pragma unroll
        for (int m = 0; m < MIDq; m++) {
            const float* wp = wic + (size_t)m * (Cq * 9);
            float w00 = wp[0], w01 = wp[1], w02 = wp[2];
            float w10 = wp[3], w11 = wp[4], w12 = wp[5];
            float w20 = wp[6], w21 = wp[7], w22 = wp[8];
#pragma unroll
            for (int o = 0; o < 4; o++) {
                float a = acc[m][o];
                a = fmaf(w00, in0[o], fmaf(w01, in0[o + 1], fmaf(w02, in0[o + 2], a)));
                a = fmaf(w10, in1[o], fmaf(w11, in1[o + 1], fmaf(w12, in1[o + 2], a)));
                a = fmaf(w20, in2[o], fmaf(w21, in2[o + 1], fmaf(w22, in2[o + 2], a)));
                acc[m][o] = a;
            }
        }
    }
    size_t rowoff = (size_t)y * Wq + xi;
#pragma unroll
    for (int m = 0; m < MIDq; m++) {
        float4 v;
        float a0 = acc[m][0], a1 = acc[m][1], a2 = acc[m][2], a3 = acc[m][3];
        v.x = a0 * sigmoidf_(a0);
        v.y = a1 * sigmoidf_(a1);
        v.z = a2 * sigmoidf_(a2);
        v.w = a3 * sigmoidf_(a3);
        *(float4*)(f1 + (size_t)(l * MIDq + m) * HWq + rowoff) = v;
    }
}

// conv2: R13-exact.
__global__ __launch_bounds__(128, 4) void k_conv2(const float* __restrict__ f1,
                        const float* __restrict__ w2,
                        const float* __restrict__ b2, float* __restrict__ f) {
    int b = blockIdx.x;
    int l = b & 7, y = b >> 3;
    int t = threadIdx.x;
    if (t >= 120) return;
    int xi = t * 4;
    float acc[2][4];
#pragma unroll
    for (int m = 0; m < 2; m++) {
        float bv = b2[m];
#pragma unroll
        for (int o = 0; o < 4; o++) acc[m][o] = bv;
    }
    int yy0 = y > 0 ? y - 1 : 0;
    int yy2 = y < Hq - 1 ? y + 1 : Hq - 1;
    float v0 = y > 0 ? 1.f : 0.f;
    float v2 = y < Hq - 1 ? 1.f : 0.f;
    bool lok = xi > 0, rok = xi + 4 < Wq;
    const float* fb = f1 + (size_t)l * MIDq * HWq;
#pragma unroll 1
    for (int ic = 0; ic < MIDq; ic++) {
        const float* p0 = fb + (size_t)ic * HWq + yy0 * Wq;
        const float* p1 = fb + (size_t)ic * HWq + y * Wq;
        const float* p2 = fb + (size_t)ic * HWq + yy2 * Wq;
        float4 m0 = *(const float4*)(p0 + xi);
        float4 m1 = *(const float4*)(p1 + xi);
        float4 m2 = *(const float4*)(p2 + xi);
        float l0 = lok ? p0[xi - 1] : 0.f;
        float l1 = lok ? p1[xi - 1] : 0.f;
        float l2 = lok ? p2[xi - 1] : 0.f;
        float r0 = rok ? p0[xi + 4] : 0.f;
        float r1 = rok ? p1[xi + 4] : 0.f;
        float r2 = rok ? p2[xi + 4] : 0.f;
        float in0[6] = {l0 * v0, m0.x * v0, m0.y * v0, m0.z * v0, m0.w * v0, r0 * v0};
        float in1[6] = {l1, m1.x, m1.y, m1.z, m1.w, r1};
        float in2[6] = {l2 * v2, m2.x * v2, m2.y * v2, m2.z * v2, m2.w * v2, r2 * v2};
        const float* wic = w2 + ic * 9;
#pragma unroll
        for (int m = 0; m < 2; m++) {
            const float* wp = wic + (size_t)m * (MIDq * 9);
            float w00 = wp[0], w01 = wp[1], w02 = wp[2];
            float w10 = wp[3], w11 = wp[4], w12 = wp[5];
            float w20 = wp[6], w21 = wp[7], w22 = wp[8];
#pragma unroll
            for (int o = 0; o < 4; o++) {
                float a = acc[m][o];
                a = fmaf(w00, in0[o], fmaf(w01, in0[o + 1], fmaf(w02, in0[o + 2], a)));
                a = fmaf(w10, in1[o], fmaf(w11, in1[o + 1], fmaf(w12, in1[o + 2], a)));
                a = fmaf(w20, in2[o], fmaf(w21, in2[o + 1], fmaf(w22, in2[o + 2], a)));
                acc[m][o] = a;
            }
        }
    }
    size_t rowoff = (size_t)y * Wq + xi;
#pragma unroll
    for (int m = 0; m < 2; m++) {
        float4 v = {acc[m][0], acc[m][1], acc[m][2], acc[m][3]};
        *(float4*)(f + (size_t)(l * 2 + m) * HWq + rowoff) = v;
    }
}

// sobel (wrap-x, edge-y) + metric + tanh -> flow (L,2,H,W) (R5 exact)
__global__ void k_flow(const float* __restrict__ f, float* __restrict__ flow) {
    int idx = blockIdx.x * blockDim.x + threadIdx.x;
    if (idx >= Lq * HWq) return;
    int l = idx / HWq, rem = idx % HWq, y = rem / Wq, x = rem % Wq;
    const float* phi = f + (size_t)(l * 2 + 0) * HWq;
    const float* psi = f + (size_t)(l * 2 + 1) * HWq;
    float ph[3][3], ps[3][3];
#pragma unroll
    for (int i = 0; i < 3; i++) {
        int yy = y + i - 1;
        yy = yy < 0 ? 0 : (yy >= Hq ? Hq - 1 : yy);
#pragma unroll
        for (int j = 0; j < 3; j++) {
            int xx = x + j - 1;
            xx = (xx + Wq) % Wq;
            ph[i][j] = phi[yy * Wq + xx];
            ps[i][j] = psi[yy * Wq + xx];
        }
    }
    float gxp = (ph[0][2] - ph[0][0]) + 2.f * (ph[1][2] - ph[1][0]) + (ph[2][2] - ph[2][0]);
    float gyp = (ph[2][0] + 2.f * ph[2][1] + ph[2][2]) - (ph[0][0] + 2.f * ph[0][1] + ph[0][2]);
    float gxs = (ps[0][2] - ps[0][0]) + 2.f * (ps[1][2] - ps[1][0]) + (ps[2][2] - ps[2][0]);
    float gys = (ps[2][0] + 2.f * ps[2][1] + ps[2][2]) - (ps[0][0] + 2.f * ps[0][1] + ps[0][2]);
    float latf = (float)(-M_PI * 0.5 + (double)y * (M_PI / (double)(Hq - 1)));
    float metric = (float)(1.0 / (cos((double)latf) + 1e-6));
    float u = gxp * metric - gys;
    float v = gyp + gxs * metric;
    flow[(size_t)(l * 2 + 0) * HWq + rem] = tanhf(u);
    flow[(size_t)(l * 2 + 1) * HWq + rem] = tanhf(v);
}

// one-time: m0[px][c] = mean_r h0[c][px][r] -> fp16 (h0: (C,H,W,R) fp32)
__global__ void k_m0(const float* __restrict__ h0, h8* __restrict__ m0) {
    int px = blockIdx.x * 256 + threadIdx.x;
    const float4* h4 = (const float4*)h0;
#pragma unroll
    for (int half = 0; half < 2; half++) {
        h8 o;
#pragma unroll
        for (int cc = 0; cc < 8; cc++) {
            int c = half * 8 + cc;
            float4 a = h4[(size_t)(c * HWq + px) * 2];
            float4 b = h4[(size_t)(c * HWq + px) * 2 + 1];
            o.v[cc] = __float2half((a.x + a.y + a.z + a.w + b.x + b.y + b.z + b.w) * 0.125f);
        }
        m0[(size_t)px * 2 + half] = o;
    }
}

// Fused scan step (R19 exact: fp16 m, one 16B gather per corner per lane).
__global__ __launch_bounds__(1024) void k_step(const h8* __restrict__ min_,
                       h8* __restrict__ mout, const float* __restrict__ flow_l,
                       const float* __restrict__ xl, const float* __restrict__ listT,
                       int l,
                       const float* __restrict__ sw1, const float* __restrict__ sb1,
                       const float* __restrict__ sw2, const float* __restrict__ sb2,
                       float* __restrict__ out_l) {
    constexpr int STR = 17;
    __shared__ float sm[Wq * STR];
    __shared__ float csum[Cq];
    __shared__ float zl[SEM];
    __shared__ float gl[Cq];

    int y = blockIdx.x;
    int t = threadIdx.x;
    int wave = t >> 6, lane = t & 63;
    bool act = t < 2 * Wq;
    int px = act ? (t >> 1) : (Wq - 1);
    int half = t & 1;
    int c0 = half * 8;

    float dt = listT[l];
    float mn[8];
    {
        float u = flow_l[y * Wq + px];
        float v = flow_l[HWq + y * Wq + px];
        float gx = (px * (2.0f / (Wq - 1)) - 1.0f) - u * dt;
        float gy = (y * (2.0f / (Hq - 1)) - 1.0f) - v * dt;
        float xp = fminf(fmaxf((gx + 1.0f) * (Wq * 0.5f) - 0.5f, 0.0f), (float)(Wq - 1));
        float yp = fminf(fmaxf((gy + 1.0f) * (Hq * 0.5f) - 0.5f, 0.0f), (float)(Hq - 1));
        float x0f = floorf(xp), y0f = floorf(yp);
        float wx = xp - x0f, wy = yp - y0f;
        int x0 = (int)x0f, y0 = (int)y0f;
        int x1 = min(x0 + 1, Wq - 1), y1 = min(y0 + 1, Hq - 1);
        h8 A = min_[(size_t)(y0 * Wq + x0) * 2 + half];
        h8 B = min_[(size_t)(y0 * Wq + x1) * 2 + half];
        h8 C = min_[(size_t)(y1 * Wq + x0) * 2 + half];
        h8 D = min_[(size_t)(y1 * Wq + x1) * 2 + half];
        float w00 = (1.f - wx) * (1.f - wy), w01 = wx * (1.f - wy);
        float w10 = (1.f - wx) * wy, w11 = wx * wy;
        const float* xb = xl + y * Wq + px;
#pragma unroll
        for (int j = 0; j < 8; j++) {
            float xv = xb[(size_t)(c0 + j) * HWq];
            mn[j] = w00 * __half2float(A.v[j]) + w01 * __half2float(B.v[j]) +
                    w10 * __half2float(C.v[j]) + w11 * __half2float(D.v[j]) + xv;
        }
    }
    if (act) {
        h8 o;
#pragma unroll
        for (int j = 0; j < 8; j++) o.v[j] = __float2half(mn[j]);
        mout[(size_t)(y * Wq + px) * 2 + half] = o;
#pragma unroll
        for (int j = 0; j < 8; j++) sm[px * STR + c0 + j] = mn[j];
    }
    __syncthreads();
    {
        float s = 0.f;
#pragma unroll
        for (int k = 0; k < 8; k++) {
            int p = k * 64 + lane;
            if (p < Wq) s += sm[p * STR + wave];
        }
#pragma unroll
        for (int off = 32; off > 0; off >>= 1) s += __shfl_down(s, off, 64);
        if (lane == 0) csum[wave] = s;
    }
    __syncthreads();
    if (t < SEM) {
        float a = sb1[t];
#pragma unroll
        for (int i = 0; i < Cq; i++) a = fmaf(sw1[t * Cq + i], csum[i] * (1.0f / Wq), a);
        zl[t] = a * sigmoidf_(a);
    }
    __syncthreads();
    if (t < Cq) {
        float a = sb2[t];
#pragma unroll
        for (int m = 0; m < SEM; m++) a = fmaf(sw2[t * SEM + m], zl[m], a);
        gl[t] = sigmoidf_(a);
    }
    __syncthreads();
    if (act) {
        float* ob = out_l + y * Wq + px;
#pragma unroll
        for (int j = 0; j < 8; j++)
            ob[(size_t)(c0 + j) * HWq] = mn[j] * gl[c0 + j];
    }
}

extern "C" void kernel_launch(void* const* d_in, const int* in_sizes, int n_in,
                              void* d_out, int out_size, void* d_ws, size_t ws_size,
                              hipStream_t stream) {
    const float* x = (const float*)d_in[0];
    const float* h0 = (const float*)d_in[1];
    const float* listT = (const float*)d_in[2];
    const float* hw1 = (const float*)d_in[3];
    const float* hb1 = (const float*)d_in[4];
    const float* hw2 = (const float*)d_in[5];
    const float* hb2 = (const float*)d_in[6];
    const float* sw1 = (const float*)d_in[7];
    const float* sb1 = (const float*)d_in[8];
    const float* sw2 = (const float*)d_in[9];
    const float* sb2 = (const float*)d_in[10];
    float* out = (float*)d_out;
    char* ws = (char*)d_ws;

    size_t off = 0;
    float* flow = (float*)(ws + off); off += sizeof(float) * (size_t)Lq * 2 * HWq;
    float* f    = (float*)(ws + off); off += sizeof(float) * (size_t)Lq * 2 * HWq;
    float* f1   = (float*)(ws + off); off += sizeof(float) * (size_t)Lq * MIDq * HWq;
    h8* mA      = (h8*)(ws + off);    off += sizeof(h8) * (size_t)HWq * 2;
    h8* mB      = (h8*)(ws + off);    off += sizeof(h8) * (size_t)HWq * 2;

    k_conv1<<<Lq * Hq, 128, 0, stream>>>(x, hw1, hb1, f1);
    k_conv2<<<Lq * Hq, 128, 0, stream>>>(f1, hw2, hb2, f);
    k_flow<<<(Lq * HWq + 255) / 256, 256, 0, stream>>>(f, flow);
    k_m0<<<HWq / 256, 256, 0, stream>>>(h0, mA);

    h8* bufs[2] = {mA, mB};
    for (int l = 0; l < Lq; l++) {
        h8* min_ = bufs[l & 1];
        h8* mout = bufs[(l + 1) & 1];
        k_step<<<Hq, 1024, 0, stream>>>(min_, mout, flow + (size_t)l * 2 * HWq,
                                        x + (size_t)l * Cq * HWq, listT, l,
                                        sw1, sb1, sw2, sb2,
                                        out + (size_t)l * Cq * HWq);
    }
}